// Round 4
// baseline (29608.954 us; speedup 1.0000x reference)
//
#include <hip/hip_runtime.h>
#include <cstdint>
#include <cstddef>

// Decoder (DA-RNN): B=512, T=256, E=D=256.
// Round 6: w1_hc register-resident as NAMED SSA values (R5's arrays went to
// scratch: VGPR=64, WRITE_SIZE=137MB). Geometry: 256 blocks x 512 threads,
// 2 rows/block, 1 block/CU, 2 waves/SIMD, 256-VGPR cap via launch_bounds(512,2).
// Per-block register capacity is 512KB (threads x cap is constant!), so only
// w1_hc (256KB) fits: 32 named half8 per thread = 128 VGPR, loaded once.
// Whh (512KB) + Ph2 (256KB) remain streamed per step. Phase 3 threads own a
// full score row -> spart eliminated -> 4 barriers/step (was 5).

typedef _Float16 half8 __attribute__((ext_vector_type(8)));
typedef _Float16 half4v __attribute__((ext_vector_type(4)));
typedef _Float16 half2v __attribute__((ext_vector_type(2)));

__device__ __forceinline__ float rcpf_(float x) { return __builtin_amdgcn_rcpf(x); }
__device__ __forceinline__ float sigmoidf_(float x) { return rcpf_(1.f + __expf(-x)); }
__device__ __forceinline__ float tanhf_(float x) { return 1.f - 2.f * rcpf_(1.f + __expf(2.f * x)); }

#if defined(__has_builtin)
#if __has_builtin(__builtin_amdgcn_fdot2)
#define HAS_FDOT2 1
#endif
#endif
#ifndef HAS_FDOT2
#define HAS_FDOT2 0
#endif

__device__ __forceinline__ float fdot2_(half2v a, half2v b, float c) {
#if HAS_FDOT2
  return __builtin_amdgcn_fdot2(a, b, c, false);
#else
  return fmaf((float)a[0], (float)b[0], fmaf((float)a[1], (float)b[1], c));
#endif
}

__device__ __forceinline__ float dot8_(half8 w, half8 h, float acc) {
  acc = fdot2_(__builtin_shufflevector(w, w, 0, 1), __builtin_shufflevector(h, h, 0, 1), acc);
  acc = fdot2_(__builtin_shufflevector(w, w, 2, 3), __builtin_shufflevector(h, h, 2, 3), acc);
  acc = fdot2_(__builtin_shufflevector(w, w, 4, 5), __builtin_shufflevector(h, h, 4, 5), acc);
  acc = fdot2_(__builtin_shufflevector(w, w, 6, 7), __builtin_shufflevector(h, h, 6, 7), acc);
  return acc;
}

#define REP32(X) X(0) X(1) X(2) X(3) X(4) X(5) X(6) X(7) X(8) X(9) X(10) X(11) \
  X(12) X(13) X(14) X(15) X(16) X(17) X(18) X(19) X(20) X(21) X(22) X(23) \
  X(24) X(25) X(26) X(27) X(28) X(29) X(30) X(31)

// ---------------- prep kernels ----------------

// wT[e*256+f] = attn_w1[f*768 + 512 + e]   (transposed w1_enc, fp32)
__global__ void k_prep_wT(const float* __restrict__ w1, float* __restrict__ wT) {
  int id = blockIdx.x * 256 + threadIdx.x;
  int e = id >> 8, f = id & 255;
  wT[id] = w1[f * 768 + 512 + e];
}

// x -> fp16 (4 elems/thread), layout unchanged [b][t][e]
__global__ void k_prep_xh(const float* __restrict__ x, _Float16* __restrict__ xh) {
  int id = blockIdx.x * 256 + threadIdx.x;
  float4 v = reinterpret_cast<const float4*>(x)[id];
  half4v h;
  h[0] = (_Float16)v.x; h[1] = (_Float16)v.y; h[2] = (_Float16)v.z; h[3] = (_Float16)v.w;
  reinterpret_cast<half4v*>(xh)[id] = h;
}

// w1hcQ[(c*512 + t)*8 + m] = w1[e*768 + k], t = jk*256+e, k = jk*256 + c*8 + m,
// c in [0,32). Thread t of k_scan register-caches chunks c=0..31.
__global__ void k_prep_w1hcQ(const float* __restrict__ w1, _Float16* __restrict__ o) {
  int id = blockIdx.x * 256 + threadIdx.x;  // 131072 total
  int m = id & 7, t = (id >> 3) & 511, c = id >> 12;
  int e = t & 255, jk = t >> 8;
  int k = jk * 256 + c * 8 + m;
  o[id] = (_Float16)w1[e * 768 + k];
}

// whhG[(((jk2*16 + c)*4 + js)*256 + jo)*8 + m] = Whh[(js*256+jo)*256 + jk2*128 + c*8 + m]
// (thread (jk2,jo) streams chunks (c=0..15, js=0..3); outputs js*256+jo over
// k in [jk2*128, +128))
__global__ void k_prep_whhG(const float* __restrict__ whh, _Float16* __restrict__ o) {
  int id = blockIdx.x * 256 + threadIdx.x;  // 262144 total
  int m = id & 7, jo = (id >> 3) & 255, js = (id >> 11) & 3;
  int c = (id >> 13) & 15, jk2 = id >> 17;
  int j = js * 256 + jo, k = jk2 * 128 + c * 8 + m;
  o[id] = (_Float16)whh[j * 256 + k];
}

// xf[b*256+t] = sum_e x[b,t,e] * fcw[e]   (fp32)
__global__ __launch_bounds__(256) void k_xf(const float* __restrict__ x,
                                            const float* __restrict__ fcw,
                                            float* __restrict__ xf) {
  __shared__ float xl[16][256];
  __shared__ float fw[256];
  __shared__ float part[16][17];
  const int tid = threadIdx.x;
  const int m0 = blockIdx.x * 16;
  fw[tid] = fcw[tid];
#pragma unroll
  for (int r = 0; r < 16; ++r) xl[r][tid] = x[(size_t)(m0 + r) * 256 + tid];
  __syncthreads();
  int r = tid >> 4, p = tid & 15;
  float s = 0.f;
#pragma unroll
  for (int u = 0; u < 16; ++u) s = fmaf(xl[r][p * 16 + u], fw[p * 16 + u], s);
  part[r][p] = s;
  __syncthreads();
  if (tid < 16) {
    float t = 0.f;
#pragma unroll
    for (int p2 = 0; p2 < 16; ++p2) t += part[tid][p2];
    xf[m0 + tid] = t;
  }
}

// enc_proj GEMM + bias, store P=exp(2*encp) fp16 in layout [b][e/8][t][e%8]
__global__ __launch_bounds__(256) void k_encp(const float* __restrict__ x,
                                              const float* __restrict__ wT,
                                              const float* __restrict__ b1,
                                              _Float16* __restrict__ Ph2) {
  __shared__ __align__(16) float xl[16][256];
  const int tid = threadIdx.x;
  const int m0 = blockIdx.x * 16;
#pragma unroll
  for (int r = 0; r < 16; ++r) xl[r][tid] = x[(size_t)(m0 + r) * 256 + tid];
  __syncthreads();
  float acc[16];
#pragma unroll
  for (int r = 0; r < 16; ++r) acc[r] = 0.f;
  for (int e = 0; e < 256; e += 4) {
    float w0 = wT[(e + 0) * 256 + tid];
    float w1_ = wT[(e + 1) * 256 + tid];
    float w2_ = wT[(e + 2) * 256 + tid];
    float w3_ = wT[(e + 3) * 256 + tid];
#pragma unroll
    for (int r = 0; r < 16; ++r) {
      float4 xv = *reinterpret_cast<const float4*>(&xl[r][e]);
      acc[r] = fmaf(xv.x, w0, acc[r]);
      acc[r] = fmaf(xv.y, w1_, acc[r]);
      acc[r] = fmaf(xv.z, w2_, acc[r]);
      acc[r] = fmaf(xv.w, w3_, acc[r]);
    }
  }
  float bb = b1[tid];
  const int e = tid;
#pragma unroll
  for (int r = 0; r < 16; ++r) {
    int m = m0 + r, b = m >> 8, t = m & 255;
    float p = __expf(2.f * (acc[r] + bb));
    Ph2[((size_t)(b * 32 + (e >> 3)) * 256 + t) * 8 + (e & 7)] = (_Float16)p;
  }
}

// ---------------- the scan ----------------
// grid 256 x 512 threads; wg owns TWO batch rows; w1_hc in named registers.
__global__ __launch_bounds__(512, 2) void k_scan(
    const _Float16* __restrict__ Ph2, const _Float16* __restrict__ xh,
    const _Float16* __restrict__ w1hcQ, const _Float16* __restrict__ whhG,
    const float* __restrict__ xf, const float* __restrict__ y_hist,
    const float* __restrict__ w2g, const float* __restrict__ Wih,
    const float* __restrict__ bih, const float* __restrict__ bhh,
    const float* __restrict__ fcw, const float* __restrict__ fcb,
    const float* __restrict__ fcfw, const float* __restrict__ fcfb,
    float* __restrict__ out) {
  __shared__ __align__(16) float hc[2][512];        // fp32 [g][ h | c ]
  __shared__ __align__(16) _Float16 hcH[2][512];    // fp16 mirror for dot2
  __shared__ __align__(16) float qpart[2][2][256];  // [jk][g][e]
  __shared__ __align__(16) float Qs[2][256];        // exp(2q)
  __shared__ __align__(16) float ealpha[2][256];
  __shared__ __align__(16) float gpart[2][2][1024]; // [jk2][g][j]; aliased post-loop as cpart[2][8][256]
  __shared__ __align__(16) float w2l[256];
  __shared__ __align__(16) float Wihl[1024];
  __shared__ __align__(16) float bl[1024];
  __shared__ __align__(16) float xfL[2][256];
  __shared__ __align__(16) float yhL[2][256];
  __shared__ float redA[8], redB[8];

  const int tid = threadIdx.x;
  const int b0 = blockIdx.x * 2;
  const int hi = tid >> 8;     // 0..1 (wave-uniform: waves 0-3 -> 0, 4-7 -> 1)
  const int lo = tid & 255;
  const int wv = tid >> 6, lane = tid & 63;

  // ---- init LDS ----
  ((float*)hc)[tid] = 0.f;
  ((float*)hc)[tid + 512] = 0.f;
  ((_Float16*)hcH)[tid] = (_Float16)0.f;
  ((_Float16*)hcH)[tid + 512] = (_Float16)0.f;
  if (tid < 256) w2l[tid] = w2g[tid];
  Wihl[tid] = Wih[tid];
  Wihl[tid + 512] = Wih[tid + 512];
  bl[tid] = bih[tid] + bhh[tid];
  bl[tid + 512] = bih[tid + 512] + bhh[tid + 512];
  xfL[hi][lo] = xf[(size_t)(b0 + hi) * 256 + lo];
  yhL[hi][lo] = y_hist[(size_t)(b0 + hi) * 256 + lo];

  // ---- register-cache w1_hc slice: 32 NAMED half8 (128 VGPR), loaded once ----
  // thread = (jk = hi, e = lo); k in [jk*256, +256), chunk c covers k-bytes c*16..
  const half8* wqp = reinterpret_cast<const half8*>(w1hcQ) + tid;
#define WQ_DECL(c) half8 wq##c = wqp[(c) * 512];
  REP32(WQ_DECL)
#undef WQ_DECL

  __syncthreads();

  float w2sum = 0.f;
  for (int e2 = 0; e2 < 256; ++e2) w2sum += w2l[e2];
  const float fcb0 = fcb[0];
  const float fcwy = fcw[256];

  // gates role: thread (jk2 = hi, jo = lo); outputs js*256+jo, k in [jk2*128,+128)
  const half8* wgs = reinterpret_cast<const half8*>(whhG) + (size_t)hi * 16384 + lo;
  // scores role: thread (g = hi, t = lo), full e-range
  const half8* prow = reinterpret_cast<const half8*>(Ph2) + ((size_t)(b0 + hi) * 32) * 256 + lo;
  const int g4 = hi * 4;

#pragma unroll 1
  for (int s = 0; s < 256; ++s) {
    // ---- phase 1: q[e] partials from registers, k-split 2, both rows ----
    float a0 = 0.f, a1 = 0.f;
    {
      const half8* hp0 = reinterpret_cast<const half8*>(&hcH[0][hi * 256]);
      const half8* hp1 = reinterpret_cast<const half8*>(&hcH[1][hi * 256]);
#define WQ_DOT(c) { half8 h0_ = hp0[c]; half8 h1_ = hp1[c]; \
      a0 = dot8_(wq##c, h0_, a0); a1 = dot8_(wq##c, h1_, a1); }
      REP32(WQ_DOT)
#undef WQ_DOT
    }
    qpart[hi][0][lo] = a0;
    qpart[hi][1][lo] = a1;
    __syncthreads();  // B1

    // ---- phase 2: Qs (all threads) + gates GEMV h@Whh (streamed weights) ----
    {
      float qv = qpart[0][hi][lo] + qpart[1][hi][lo];
      Qs[hi][lo] = __expf(2.f * qv);
    }
    float ac00 = 0.f, ac01 = 0.f, ac02 = 0.f, ac03 = 0.f;
    float ac10 = 0.f, ac11 = 0.f, ac12 = 0.f, ac13 = 0.f;
    {
      const half8* hg0 = reinterpret_cast<const half8*>(&hcH[0][hi * 128]);
      const half8* hg1 = reinterpret_cast<const half8*>(&hcH[1][hi * 128]);
#pragma unroll
      for (int c = 0; c < 16; ++c) {
        half8 w0 = wgs[c * 1024];
        half8 w1v = wgs[c * 1024 + 256];
        half8 w2v = wgs[c * 1024 + 512];
        half8 w3v = wgs[c * 1024 + 768];
        half8 h0 = hg0[c];  // broadcast LDS read
        half8 h1 = hg1[c];
        ac00 = dot8_(w0, h0, ac00);  ac10 = dot8_(w0, h1, ac10);
        ac01 = dot8_(w1v, h0, ac01); ac11 = dot8_(w1v, h1, ac11);
        ac02 = dot8_(w2v, h0, ac02); ac12 = dot8_(w2v, h1, ac12);
        ac03 = dot8_(w3v, h0, ac03); ac13 = dot8_(w3v, h1, ac13);
      }
    }
    gpart[hi][0][lo] = ac00;
    gpart[hi][0][256 + lo] = ac01;
    gpart[hi][0][512 + lo] = ac02;
    gpart[hi][0][768 + lo] = ac03;
    gpart[hi][1][lo] = ac10;
    gpart[hi][1][256 + lo] = ac11;
    gpart[hi][1][512 + lo] = ac12;
    gpart[hi][1][768 + lo] = ac13;
    __syncthreads();  // B2

    // ---- phase 3: scores, full e-range per thread: sc = w2sum - 2*sum w2/(PQ+1) ----
    float sacc0 = 0.f, sacc1 = 0.f;
    {
      const float4* q4 = reinterpret_cast<const float4*>(&Qs[hi][0]);
      const float4* w4 = reinterpret_cast<const float4*>(&w2l[0]);
#pragma unroll
      for (int c = 0; c < 32; ++c) {
        half8 pv = __builtin_nontemporal_load(prow + c * 256);
        float4 qa = q4[2 * c], wa = w4[2 * c];
        sacc0 = fmaf(wa.x, rcpf_(fmaf((float)pv[0], qa.x, 1.f)), sacc0);
        sacc1 = fmaf(wa.y, rcpf_(fmaf((float)pv[1], qa.y, 1.f)), sacc1);
        sacc0 = fmaf(wa.z, rcpf_(fmaf((float)pv[2], qa.z, 1.f)), sacc0);
        sacc1 = fmaf(wa.w, rcpf_(fmaf((float)pv[3], qa.w, 1.f)), sacc1);
        float4 qb = q4[2 * c + 1], wb = w4[2 * c + 1];
        sacc0 = fmaf(wb.x, rcpf_(fmaf((float)pv[4], qb.x, 1.f)), sacc0);
        sacc1 = fmaf(wb.y, rcpf_(fmaf((float)pv[5], qb.y, 1.f)), sacc1);
        sacc0 = fmaf(wb.z, rcpf_(fmaf((float)pv[6], qb.z, 1.f)), sacc0);
        sacc1 = fmaf(wb.w, rcpf_(fmaf((float)pv[7], qb.w, 1.f)), sacc1);
      }
    }
    {
      float sc = w2sum - 2.f * (sacc0 + sacc1);
      float ea = __expf(sc);  // no max-sub: |sc| <= ~21, fp32-safe
      ealpha[hi][lo] = ea;
      float ef = ea * xfL[hi][lo];
      float es = ea;
#pragma unroll
      for (int off = 32; off > 0; off >>= 1) {
        es += __shfl_xor(es, off);
        ef += __shfl_xor(ef, off);
      }
      if (lane == 0) { redA[wv] = es; redB[wv] = ef; }
    }
    __syncthreads();  // B3

    // ---- phase 4: softmax combine + LSTM pointwise (all threads; g = hi) ----
    {
      float es = redA[g4 + 0] + redA[g4 + 1] + redA[g4 + 2] + redA[g4 + 3];
      float ef = redB[g4 + 0] + redB[g4 + 1] + redB[g4 + 2] + redB[g4 + 3];
      float yt = ef * rcpf_(es) + fmaf(yhL[hi][s], fcwy, fcb0);
      float gi = fmaf(yt, Wihl[lo], bl[lo]);
      float gf = fmaf(yt, Wihl[256 + lo], bl[256 + lo]);
      float gc = fmaf(yt, Wihl[512 + lo], bl[512 + lo]);
      float go = fmaf(yt, Wihl[768 + lo], bl[768 + lo]);
      gi += gpart[0][hi][lo] + gpart[1][hi][lo];
      gf += gpart[0][hi][256 + lo] + gpart[1][hi][256 + lo];
      gc += gpart[0][hi][512 + lo] + gpart[1][hi][512 + lo];
      go += gpart[0][hi][768 + lo] + gpart[1][hi][768 + lo];
      float iv = sigmoidf_(gi), fv = sigmoidf_(gf), gv = tanhf_(gc), ov = sigmoidf_(go);
      float cold = hc[hi][256 + lo];
      float cn = fmaf(fv, cold, iv * gv);
      float hn = ov * tanhf_(cn);
      hc[hi][lo] = hn;
      hc[hi][256 + lo] = cn;
      hcH[hi][lo] = (_Float16)hn;
      hcH[hi][256 + lo] = (_Float16)cn;
    }
    __syncthreads();  // B4
  }

  // ---- epilogue: context from step-255 ealpha, then out = [h|ctx].fcf ----
  // read last-step softmax sums BEFORE redA/redB get reused
  const float rsA = rcpf_(redA[0] + redA[1] + redA[2] + redA[3]);
  const float rsB = rcpf_(redA[4] + redA[5] + redA[6] + redA[7]);

  float* cpartF = &gpart[0][0][0];  // alias: cpart[g][u][t] = cpartF[(g*8+u)*256+t]
  {
    const int ts = (tid >> 5) & 7;   // t-slice (32 t each)
    const int l5 = tid & 31;         // e-chunk (8 e each)
    const half8* xrow = reinterpret_cast<const half8*>(xh) +
                        ((size_t)(b0 + hi) * 256 + ts * 32) * 32 + l5;
    float acx[8];
#pragma unroll
    for (int m = 0; m < 8; ++m) acx[m] = 0.f;
#pragma unroll 4
    for (int it = 0; it < 32; ++it) {
      float al = ealpha[hi][ts * 32 + it];
      half8 xv = xrow[it * 32];
#pragma unroll
      for (int m = 0; m < 8; ++m) acx[m] = fmaf(al, (float)xv[m], acx[m]);
    }
    float* dst = &cpartF[((hi * 8 + ts) * 256) + l5 * 8];
    *reinterpret_cast<float4*>(dst) = *reinterpret_cast<float4*>(&acx[0]);
    *reinterpret_cast<float4*>(dst + 4) = *reinterpret_cast<float4*>(&acx[4]);
  }
  __syncthreads();

  {
    float cv = 0.f;
#pragma unroll
    for (int u = 0; u < 8; ++u) cv += cpartF[((hi * 8 + u) * 256) + lo];
    cv *= (hi == 0) ? rsA : rsB;
    float hval = hc[hi][lo];
    float p0 = hval * fcfw[lo] + cv * fcfw[256 + lo];
    float p1 = hval * fcfw[512 + lo] + cv * fcfw[768 + lo];
#pragma unroll
    for (int off = 32; off > 0; off >>= 1) {
      p0 += __shfl_xor(p0, off);
      p1 += __shfl_xor(p1, off);
    }
    if (lane == 0) { redA[wv] = p0; redB[wv] = p1; }
  }
  __syncthreads();
  if (tid < 4) {
    int gg = tid >> 1, o = tid & 1;
    const float* r = (o == 0) ? redA : redB;
    float v = fcfb[o] + r[gg * 4 + 0] + r[gg * 4 + 1] + r[gg * 4 + 2] + r[gg * 4 + 3];
    out[(b0 + gg) * 2 + o] = v;
  }
}

extern "C" void kernel_launch(void* const* d_in, const int* in_sizes, int n_in,
                              void* d_out, int out_size, void* d_ws, size_t ws_size,
                              hipStream_t stream) {
  (void)in_sizes; (void)n_in; (void)out_size; (void)ws_size;
  const float* x    = (const float*)d_in[0];
  const float* yh   = (const float*)d_in[1];
  const float* w1   = (const float*)d_in[2];
  const float* b1   = (const float*)d_in[3];
  const float* w2   = (const float*)d_in[4];
  /* d_in[5] attn_b2: softmax-invariant, unused */
  const float* Wih  = (const float*)d_in[6];
  const float* Whh  = (const float*)d_in[7];
  const float* bih  = (const float*)d_in[8];
  const float* bhh  = (const float*)d_in[9];
  const float* fcw  = (const float*)d_in[10];
  const float* fcb  = (const float*)d_in[11];
  const float* fcfw = (const float*)d_in[12];
  const float* fcfb = (const float*)d_in[13];
  float* out = (float*)d_out;

  char* ws = (char*)d_ws;
  _Float16* Ph2   = (_Float16*)(ws);                      // 67108864 B
  _Float16* xh    = (_Float16*)(ws + (size_t)67108864);   // 67108864 B
  float*    wT    = (float*)   (ws + (size_t)134217728);  // 262144 B
  _Float16* w1hcQ = (_Float16*)(ws + (size_t)134479872);  // 262144 B
  _Float16* whhG  = (_Float16*)(ws + (size_t)134742016);  // 524288 B
  float*    xf    = (float*)   (ws + (size_t)135266304);  // 524288 B
  // total: 135790592 B (~129.5 MB)

  k_prep_wT   <<<256,   256, 0, stream>>>(w1, wT);
  k_prep_xh   <<<32768, 256, 0, stream>>>(x, xh);
  k_prep_w1hcQ<<<512,   256, 0, stream>>>(w1, w1hcQ);
  k_prep_whhG <<<1024,  256, 0, stream>>>(Whh, whhG);
  k_xf        <<<8192,  256, 0, stream>>>(x, fcw, xf);
  k_encp      <<<8192,  256, 0, stream>>>(x, wT, b1, Ph2);
  k_scan      <<<256,   512, 0, stream>>>(Ph2, xh, w1hcQ, whhG, xf, yh, w2, Wih,
                                          bih, bhh, fcw, fcb, fcfw, fcfb, out);
}